// Round 12
// baseline (2836.909 us; speedup 1.0000x reference)
//
#include <hip/hip_runtime.h>
#include <hip/hip_fp8.h>
#include <hip/hip_fp16.h>
#include <stdint.h>

#define FP8_MAX_V 448.0f

typedef float f32x16 __attribute__((ext_vector_type(16)));
typedef int i32x4 __attribute__((ext_vector_type(4)));
typedef int i32x8 __attribute__((ext_vector_type(8)));

__device__ __forceinline__ uint8_t cvt_fp8(float v) {
    return __hip_cvt_float_to_fp8(fminf(fmaxf(v, -FP8_MAX_V), FP8_MAX_V),
                                  __HIP_SATFINITE, __HIP_E4M3);
}

// ---------------- probe weight transport dtype + init amax ----------------
__global__ void fp8lin_probe(const uint32_t* __restrict__ w, unsigned* __restrict__ flag,
                             unsigned* __restrict__ amax_bits) {
    __shared__ unsigned s32, s16, s4;
    if (threadIdx.x == 0) { s32 = 0u; s16 = 0u; s4 = 0u; *amax_bits = 0u; }
    __syncthreads();
    unsigned o32 = 0u, o16 = 0u, o4 = 0u;
    for (int i = threadIdx.x; i < 4096; i += 256) {
        uint32_t v = w[i];
        o32 |= v & 0x000FFFFFu;
        uint32_t h0 = v & 0xFFFFu, h1 = v >> 16;
        o16 |= (h0 & 0x7Fu) | (h1 & 0x7Fu);
        o4  |= (h0 & 0x0Fu) | (h1 & 0x0Fu);
    }
    atomicOr(&s32, o32); atomicOr(&s16, o16); atomicOr(&s4, o4);
    __syncthreads();
    if (threadIdx.x == 0)
        *flag = (s32 == 0u) ? 0u : (s16 == 0u) ? 1u : (s4 == 0u) ? 2u : 3u;
}

// ---------------- amax (per-tensor, exact) ----------------
__global__ void fp8lin_amax(const float4* __restrict__ x, unsigned* __restrict__ amax_bits, long n4) {
    float m = 0.f;
    long stride = (long)gridDim.x * blockDim.x;
    for (long i = blockIdx.x * (long)blockDim.x + threadIdx.x; i < n4; i += stride) {
        float4 v = x[i];
        m = fmaxf(m, fmaxf(fmaxf(fabsf(v.x), fabsf(v.y)), fmaxf(fabsf(v.z), fabsf(v.w))));
    }
#pragma unroll
    for (int o = 32; o; o >>= 1) m = fmaxf(m, __shfl_xor(m, o));
    if ((threadIdx.x & 63) == 0) atomicMax(amax_bits, __float_as_uint(m));
}

// ---------------- quantize x -> fp8 e4m3fn (scale derived inline) ----------------
__global__ void fp8lin_quant(const float4* __restrict__ x, const unsigned* __restrict__ amax_bits,
                             uchar4* __restrict__ xq, long n4) {
    float s = fmaxf(__uint_as_float(*amax_bits), 1e-12f) / FP8_MAX_V;
    long stride = (long)gridDim.x * blockDim.x;
    for (long i = blockIdx.x * (long)blockDim.x + threadIdx.x; i < n4; i += stride) {
        float4 v = x[i];
        uchar4 o;
        o.x = cvt_fp8(v.x / s); o.y = cvt_fp8(v.y / s);
        o.z = cvt_fp8(v.z / s); o.w = cvt_fp8(v.w / s);
        xq[i] = o;
    }
}

// ---- convert + PACK weight into MFMA-fragment order ----
// pack unit (nt,kt) = 2048 B: lane l = r + 32q holds W[nt*32+r][kt*64+32q .. +32).
__global__ void fp8lin_packw(const void* __restrict__ wsrc, const unsigned* __restrict__ flag,
                             uint8_t* __restrict__ pack, int N, int K) {
    const int NKT = K >> 6;
    const long units = ((long)N * K) >> 6;   // one thread per 64-B k-chunk of one row
    unsigned f = *flag;
    long stride = (long)gridDim.x * blockDim.x;
    for (long u = blockIdx.x * (long)blockDim.x + threadIdx.x; u < units; u += stride) {
        int r = (int)(u & 31);
        long v = u >> 5;                     // nt*NKT + kt
        long row = (v / NKT) * 32 + r;
        long kbase = (long)(v % NKT) * 64;
        uint32_t wv[16];
        if (f == 0u) {
            const float4* s = (const float4*)((const float*)wsrc + row * K + kbase);
#pragma unroll
            for (int i = 0; i < 16; ++i) {
                float4 t = s[i];
                uint32_t a = (uint32_t)cvt_fp8(t.x) | ((uint32_t)cvt_fp8(t.y) << 8) |
                             ((uint32_t)cvt_fp8(t.z) << 16) | ((uint32_t)cvt_fp8(t.w) << 24);
                wv[i] = a;
            }
        } else if (f == 1u) {
            const __half* s = (const __half*)wsrc + row * K + kbase;
#pragma unroll
            for (int i = 0; i < 16; ++i) {
                uint32_t a = 0;
#pragma unroll
                for (int j = 0; j < 4; ++j) a |= (uint32_t)cvt_fp8(__half2float(s[4 * i + j])) << (8 * j);
                wv[i] = a;
            }
        } else if (f == 2u) {
            const uint16_t* s = (const uint16_t*)wsrc + row * K + kbase;
#pragma unroll
            for (int i = 0; i < 16; ++i) {
                uint32_t a = 0;
#pragma unroll
                for (int j = 0; j < 4; ++j)
                    a |= (uint32_t)cvt_fp8(__uint_as_float((uint32_t)s[4 * i + j] << 16)) << (8 * j);
                wv[i] = a;
            }
        } else {
            const uint32_t* s = (const uint32_t*)((const uint8_t*)wsrc + row * K + kbase);
#pragma unroll
            for (int i = 0; i < 16; ++i) wv[i] = s[i];
        }
        uint8_t* d0 = pack + (v * 64 + r) * 32;        // q=0 half
        uint8_t* d1 = pack + (v * 64 + 32 + r) * 32;   // q=1 half
        i32x4 lo0 = { (int)wv[0], (int)wv[1], (int)wv[2], (int)wv[3] };
        i32x4 lo1 = { (int)wv[4], (int)wv[5], (int)wv[6], (int)wv[7] };
        i32x4 hi0 = { (int)wv[8], (int)wv[9], (int)wv[10], (int)wv[11] };
        i32x4 hi1 = { (int)wv[12], (int)wv[13], (int)wv[14], (int)wv[15] };
        *(i32x4*)(d0) = lo0; *(i32x4*)(d0 + 16) = lo1;
        *(i32x4*)(d1) = hi0; *(i32x4*)(d1 + 16) = hi1;
    }
}

// ---- fp8 GEMM: 256x128 tile, BK=128, 4 waves, MX 32x32x64, A LDS dbuf, B pack ----
// BK=128 halves the barrier/vmcnt cadence per FLOP vs BK=64 (R11's 1690 cy/tile overhead).
// A tile = two stacked 256x64 subtiles -> keeps the verified 64B-pitch XOR swizzle.
#define BM 256
#define BN 128
#define BK 128
#define SUBOFF 16384                  // second 256x64 subtile
#define A_TILE 32768
#define BUF_BYTES A_TILE
#define SMEM_BYTES (2 * A_TILE)       // 64 KiB double-buffered -> 2 blocks/CU

__device__ __forceinline__ void gload16(const uint8_t* src, uint8_t* ldst) {
    __builtin_amdgcn_global_load_lds(
        (const __attribute__((address_space(1))) uint32_t*)(uintptr_t)src,
        (__attribute__((address_space(3))) uint32_t*)(uintptr_t)ldst, 16, 0, 0);
}

#define WAITVM(N) asm volatile("s_waitcnt vmcnt(" #N ")" ::: "memory")
#define BARRIER() do { asm volatile("" ::: "memory"); __builtin_amdgcn_s_barrier(); \
                       asm volatile("" ::: "memory"); } while (0)

#define LDFRAG(dst, base, off) do {                                    \
    i32x4 _lo = *(const i32x4*)((base) + (off));                       \
    i32x4 _hi = *(const i32x4*)((base) + ((off) ^ 16));                \
    dst[0] = _lo[0]; dst[1] = _lo[1]; dst[2] = _lo[2]; dst[3] = _lo[3];\
    dst[4] = _hi[0]; dst[5] = _hi[1]; dst[6] = _hi[2]; dst[7] = _hi[3];\
} while (0)

#define LOADB(bv, src, koff) do {                                      \
    const uint8_t* _p = (src) + (koff);                                \
    i32x4 _l0 = *(const i32x4*)(_p);                                   \
    i32x4 _l1 = *(const i32x4*)(_p + 16);                              \
    bv[0] = _l0[0]; bv[1] = _l0[1]; bv[2] = _l0[2]; bv[3] = _l0[3];    \
    bv[4] = _l1[0]; bv[5] = _l1[1]; bv[6] = _l1[2]; bv[7] = _l1[3];    \
} while (0)

#define MFMA_MX(A, B, C) __builtin_amdgcn_mfma_scale_f32_32x32x64_f8f6f4( \
    (A), (B), (C), 0, 0, 0, (int)0x7f7f7f7f, 0, (int)0x7f7f7f7f)

// min-waves/EU = 2 (256-reg budget). Forcing 4 spilled the 128-reg acc (R6).
__global__ __launch_bounds__(256, 2) void fp8lin_gemm(
    const uint8_t* __restrict__ Aq,    // [M,K] fp8
    const uint8_t* __restrict__ Bpack, // packed W fragments
    const unsigned* __restrict__ amax_bits,
    const float* __restrict__ wscale,
    const float* __restrict__ bias,
    float* __restrict__ out,
    int M, int N, int K) {
    extern __shared__ __align__(16) uint8_t smem[];

    const int tid = threadIdx.x;
    const int wid = tid >> 6;
    const int lane = tid & 63;
    const int wm = wid >> 1;   // 0..1  (M-wave, 128 rows each)
    const int wn = wid & 1;    // 0..1  (N-wave, 64 cols each)

    // ---- bijective XCD swizzle ----
    const int nbx = gridDim.x;                       // 128
    const int orig = blockIdx.y * nbx + blockIdx.x;
    const int cpx = (gridDim.x * gridDim.y) >> 3;    // 512
    const int swzb = (orig & 7) * cpx + (orig >> 3);
    const int brow = (swzb / nbx) * BM;
    const int bcol = (swzb % nbx) * BN;

    // ---- A staging (per 64B-wide subtile): granule p of row r holds global
    // granule p ^ ((r>>1)&3) ----
    const uint8_t* srcA[4];
#pragma unroll
    for (int j = 0; j < 4; ++j) {
        int c = tid + 256 * j;
        int r = c >> 2;
        int sc = ((c & 3) ^ ((r >> 1) & 3)) * 16;
        srcA[j] = Aq + (size_t)(brow + r) * K + sc;
    }
    const int ldsW = wid * 1024;

    // ---- LDS read addressing for A fragments (within a 64B-pitch subtile) ----
    const int l31 = lane & 31;
    const int q = lane >> 5;
    const int swzr = (l31 >> 1) & 3;
    const int posl = (2 * q) ^ swzr;
    const int offA = (wm * 128 + l31) * 64 + posl * 16;  // + mi*2048 (+SUBOFF for ksub1)

    // ---- B from pack: 64-K granule kt = 2t+s; stride 2048 B per granule ----
    const int NKT = K >> 6;
    const uint8_t* srcB0 = Bpack + ((size_t)((bcol >> 5) + wn * 2) * NKT * 64 + lane) * 32;
    const uint8_t* srcB1 = srcB0 + (size_t)NKT * 2048;

    f32x16 acc[4][2];
#pragma unroll
    for (int mi = 0; mi < 4; ++mi)
#pragma unroll
        for (int ni = 0; ni < 2; ++ni)
#pragma unroll
            for (int r = 0; r < 16; ++r) acc[mi][ni][r] = 0.0f;

    auto STAGEA = [&](int t, int ib) {   // 8 gload16: two 64B subtiles
        size_t k0 = (size_t)t * BK;
        uint8_t* base = smem + ib * BUF_BYTES;
        gload16(srcA[0] + k0, base + ldsW);
        gload16(srcA[1] + k0, base + ldsW + 4096);
        gload16(srcA[2] + k0, base + ldsW + 8192);
        gload16(srcA[3] + k0, base + ldsW + 12288);
        gload16(srcA[0] + k0 + 64, base + SUBOFF + ldsW);
        gload16(srcA[1] + k0 + 64, base + SUBOFF + ldsW + 4096);
        gload16(srcA[2] + k0 + 64, base + SUBOFF + ldsW + 8192);
        gload16(srcA[3] + k0 + 64, base + SUBOFF + ldsW + 12288);
    };

    // B frag naming: bS N  (S=ksub, N=ni)
    auto COMPUTE = [&](int ib, const i32x8& b00, const i32x8& b01,
                       const i32x8& b10, const i32x8& b11) {
        const uint8_t* bA = smem + ib * BUF_BYTES;
        i32x8 aX, aY;
        // ---- ksub 0
        LDFRAG(aX, bA, offA);
        LDFRAG(aY, bA, offA + 2048);
        __builtin_amdgcn_s_setprio(1);
        acc[0][0] = MFMA_MX(aX, b00, acc[0][0]);
        acc[1][0] = MFMA_MX(aY, b00, acc[1][0]);
        acc[0][1] = MFMA_MX(aX, b01, acc[0][1]);
        acc[1][1] = MFMA_MX(aY, b01, acc[1][1]);
        __builtin_amdgcn_s_setprio(0);
        LDFRAG(aX, bA, offA + 4096);
        LDFRAG(aY, bA, offA + 6144);
        __builtin_amdgcn_s_setprio(1);
        acc[2][0] = MFMA_MX(aX, b00, acc[2][0]);
        acc[3][0] = MFMA_MX(aY, b00, acc[3][0]);
        acc[2][1] = MFMA_MX(aX, b01, acc[2][1]);
        acc[3][1] = MFMA_MX(aY, b01, acc[3][1]);
        __builtin_amdgcn_s_setprio(0);
        // ---- ksub 1
        LDFRAG(aX, bA, SUBOFF + offA);
        LDFRAG(aY, bA, SUBOFF + offA + 2048);
        __builtin_amdgcn_s_setprio(1);
        acc[0][0] = MFMA_MX(aX, b10, acc[0][0]);
        acc[1][0] = MFMA_MX(aY, b10, acc[1][0]);
        acc[0][1] = MFMA_MX(aX, b11, acc[0][1]);
        acc[1][1] = MFMA_MX(aY, b11, acc[1][1]);
        __builtin_amdgcn_s_setprio(0);
        LDFRAG(aX, bA, SUBOFF + offA + 4096);
        LDFRAG(aY, bA, SUBOFF + offA + 6144);
        __builtin_amdgcn_s_setprio(1);
        acc[2][0] = MFMA_MX(aX, b10, acc[2][0]);
        acc[3][0] = MFMA_MX(aY, b10, acc[3][0]);
        acc[2][1] = MFMA_MX(aX, b11, acc[2][1]);
        acc[3][1] = MFMA_MX(aY, b11, acc[3][1]);
        __builtin_amdgcn_s_setprio(0);
    };

    // Per tile: 16 VMEM ops (8 gload16 + 8 dwordx4 from 4 LOADB) -> WAITVM(16)
    // drains exactly the previous tile's batch.
    const int NT = K / BK;  // 32 (even)
    i32x8 bE00, bE01, bE10, bE11, bO00, bO01, bO10, bO11;   // static names (rule #20)
    LOADB(bE00, srcB0, 0); LOADB(bE01, srcB1, 0);
    LOADB(bE10, srcB0, 2048); LOADB(bE11, srcB1, 2048);
    STAGEA(0, 0);
    for (int tp = 0; tp < NT; tp += 2) {
        // even tile tp: compute buf0/E, prefetch tile tp+1 -> buf1/O
        {
            size_t kb = (size_t)(2 * (tp + 1)) * 2048;
            LOADB(bO00, srcB0, kb); LOADB(bO01, srcB1, kb);
            LOADB(bO10, srcB0, kb + 2048); LOADB(bO11, srcB1, kb + 2048);
        }
        STAGEA(tp + 1, 1);
        WAITVM(16);
        BARRIER();
        COMPUTE(0, bE00, bE01, bE10, bE11);
        BARRIER();
        // odd tile tp+1: compute buf1/O, prefetch tile tp+2 -> buf0/E
        if (tp + 2 < NT) {
            size_t kb = (size_t)(2 * (tp + 2)) * 2048;
            LOADB(bE00, srcB0, kb); LOADB(bE01, srcB1, kb);
            LOADB(bE10, srcB0, kb + 2048); LOADB(bE11, srcB1, kb + 2048);
            STAGEA(tp + 2, 0);
            WAITVM(16);
        } else {
            WAITVM(0);
        }
        BARRIER();
        COMPUTE(1, bO00, bO01, bO10, bO11);
        BARRIER();
    }

    // ---- epilogue: 32x32 C/D layout col=lane&31, row=(reg&3)+8*(reg>>2)+4*q ----
    float s = (fmaxf(__uint_as_float(*amax_bits), 1e-12f) / FP8_MAX_V) * wscale[0];
    const int colg = bcol + wn * 64 + l31;
    const int rowg0 = brow + wm * 128 + 4 * q;
#pragma unroll
    for (int ni = 0; ni < 2; ++ni) {
        int col = colg + ni * 32;
        float bv = bias[col];
#pragma unroll
        for (int mi = 0; mi < 4; ++mi) {
            int rb = rowg0 + mi * 32;
#pragma unroll
            for (int reg = 0; reg < 16; ++reg) {
                int row = rb + (reg & 3) + 8 * (reg >> 2);
                __builtin_nontemporal_store(acc[mi][ni][reg] * s + bv,
                                            out + (size_t)row * N + col);
            }
        }
    }
}

extern "C" void kernel_launch(void* const* d_in, const int* in_sizes, int n_in,
                              void* d_out, int out_size, void* d_ws, size_t ws_size,
                              hipStream_t stream) {
    const float* x = (const float*)d_in[0];
    const void* w = d_in[1];
    const float* wscale = (const float*)d_in[2];
    const float* bias = (const float*)d_in[3];
    float* out = (float*)d_out;

    const int Bb = 4, S = 2048, K = 4096, N = 16384;
    const int M = Bb * S;
    const long nx = (long)M * K;

    unsigned* amax_bits = (unsigned*)d_ws;
    unsigned* wflag = (unsigned*)((char*)d_ws + 32);
    uchar4* xq = (uchar4*)((char*)d_ws + 256);
    uint8_t* pack = (uint8_t*)((char*)d_ws + 256 + nx);

    fp8lin_probe<<<1, 256, 0, stream>>>((const uint32_t*)w, wflag, amax_bits);
    fp8lin_amax<<<2048, 256, 0, stream>>>((const float4*)x, amax_bits, nx / 4);
    fp8lin_quant<<<2048, 256, 0, stream>>>((const float4*)x, amax_bits, xq, nx / 4);
    fp8lin_packw<<<2048, 256, 0, stream>>>(w, wflag, pack, N, K);

    dim3 grid(N / BN, M / BM);   // (128, 32) = 4096 blocks
    fp8lin_gemm<<<grid, 256, SMEM_BYTES, stream>>>((const uint8_t*)xq, pack,
                                                   amax_bits, wscale, bias, out, M, N, K);
}

// Round 13
// 945.339 us; speedup vs baseline: 3.0009x; 3.0009x over previous
//
#include <hip/hip_runtime.h>
#include <hip/hip_fp8.h>
#include <hip/hip_fp16.h>
#include <stdint.h>

#define FP8_MAX_V 448.0f

typedef float f32x16 __attribute__((ext_vector_type(16)));
typedef int i32x4 __attribute__((ext_vector_type(4)));
typedef int i32x8 __attribute__((ext_vector_type(8)));

__device__ __forceinline__ uint8_t cvt_fp8(float v) {
    return __hip_cvt_float_to_fp8(fminf(fmaxf(v, -FP8_MAX_V), FP8_MAX_V),
                                  __HIP_SATFINITE, __HIP_E4M3);
}

// ---------------- probe weight transport dtype + init amax ----------------
__global__ void fp8lin_probe(const uint32_t* __restrict__ w, unsigned* __restrict__ flag,
                             unsigned* __restrict__ amax_bits) {
    __shared__ unsigned s32, s16, s4;
    if (threadIdx.x == 0) { s32 = 0u; s16 = 0u; s4 = 0u; *amax_bits = 0u; }
    __syncthreads();
    unsigned o32 = 0u, o16 = 0u, o4 = 0u;
    for (int i = threadIdx.x; i < 4096; i += 256) {
        uint32_t v = w[i];
        o32 |= v & 0x000FFFFFu;
        uint32_t h0 = v & 0xFFFFu, h1 = v >> 16;
        o16 |= (h0 & 0x7Fu) | (h1 & 0x7Fu);
        o4  |= (h0 & 0x0Fu) | (h1 & 0x0Fu);
    }
    atomicOr(&s32, o32); atomicOr(&s16, o16); atomicOr(&s4, o4);
    __syncthreads();
    if (threadIdx.x == 0)
        *flag = (s32 == 0u) ? 0u : (s16 == 0u) ? 1u : (s4 == 0u) ? 2u : 3u;
}

// ---------------- amax (per-tensor, exact) ----------------
__global__ void fp8lin_amax(const float4* __restrict__ x, unsigned* __restrict__ amax_bits, long n4) {
    float m = 0.f;
    long stride = (long)gridDim.x * blockDim.x;
    for (long i = blockIdx.x * (long)blockDim.x + threadIdx.x; i < n4; i += stride) {
        float4 v = x[i];
        m = fmaxf(m, fmaxf(fmaxf(fabsf(v.x), fabsf(v.y)), fmaxf(fabsf(v.z), fabsf(v.w))));
    }
#pragma unroll
    for (int o = 32; o; o >>= 1) m = fmaxf(m, __shfl_xor(m, o));
    if ((threadIdx.x & 63) == 0) atomicMax(amax_bits, __float_as_uint(m));
}

// ---------------- quantize x -> fp8 e4m3fn (scale derived inline) ----------------
__global__ void fp8lin_quant(const float4* __restrict__ x, const unsigned* __restrict__ amax_bits,
                             uchar4* __restrict__ xq, long n4) {
    float s = fmaxf(__uint_as_float(*amax_bits), 1e-12f) / FP8_MAX_V;
    long stride = (long)gridDim.x * blockDim.x;
    for (long i = blockIdx.x * (long)blockDim.x + threadIdx.x; i < n4; i += stride) {
        float4 v = x[i];
        uchar4 o;
        o.x = cvt_fp8(v.x / s); o.y = cvt_fp8(v.y / s);
        o.z = cvt_fp8(v.z / s); o.w = cvt_fp8(v.w / s);
        xq[i] = o;
    }
}

// ---- convert + PACK weight into MFMA-fragment order ----
// pack unit (nt,kt) = 2048 B: lane l = r + 32q holds W[nt*32+r][kt*64+32q .. +32).
__global__ void fp8lin_packw(const void* __restrict__ wsrc, const unsigned* __restrict__ flag,
                             uint8_t* __restrict__ pack, int N, int K) {
    const int NKT = K >> 6;
    const long units = ((long)N * K) >> 6;   // one thread per 64-B k-chunk of one row
    unsigned f = *flag;
    long stride = (long)gridDim.x * blockDim.x;
    for (long u = blockIdx.x * (long)blockDim.x + threadIdx.x; u < units; u += stride) {
        int r = (int)(u & 31);
        long v = u >> 5;                     // nt*NKT + kt
        long row = (v / NKT) * 32 + r;
        long kbase = (long)(v % NKT) * 64;
        uint32_t wv[16];
        if (f == 0u) {
            const float4* s = (const float4*)((const float*)wsrc + row * K + kbase);
#pragma unroll
            for (int i = 0; i < 16; ++i) {
                float4 t = s[i];
                wv[i] = (uint32_t)cvt_fp8(t.x) | ((uint32_t)cvt_fp8(t.y) << 8) |
                        ((uint32_t)cvt_fp8(t.z) << 16) | ((uint32_t)cvt_fp8(t.w) << 24);
            }
        } else if (f == 1u) {
            const __half* s = (const __half*)wsrc + row * K + kbase;
#pragma unroll
            for (int i = 0; i < 16; ++i) {
                uint32_t a = 0;
#pragma unroll
                for (int j = 0; j < 4; ++j) a |= (uint32_t)cvt_fp8(__half2float(s[4 * i + j])) << (8 * j);
                wv[i] = a;
            }
        } else if (f == 2u) {
            const uint16_t* s = (const uint16_t*)wsrc + row * K + kbase;
#pragma unroll
            for (int i = 0; i < 16; ++i) {
                uint32_t a = 0;
#pragma unroll
                for (int j = 0; j < 4; ++j)
                    a |= (uint32_t)cvt_fp8(__uint_as_float((uint32_t)s[4 * i + j] << 16)) << (8 * j);
                wv[i] = a;
            }
        } else {
            const uint32_t* s = (const uint32_t*)((const uint8_t*)wsrc + row * K + kbase);
#pragma unroll
            for (int i = 0; i < 16; ++i) wv[i] = s[i];
        }
        uint8_t* d0 = pack + (v * 64 + r) * 32;        // q=0 half
        uint8_t* d1 = pack + (v * 64 + 32 + r) * 32;   // q=1 half
        i32x4 lo0 = { (int)wv[0], (int)wv[1], (int)wv[2], (int)wv[3] };
        i32x4 lo1 = { (int)wv[4], (int)wv[5], (int)wv[6], (int)wv[7] };
        i32x4 hi0 = { (int)wv[8], (int)wv[9], (int)wv[10], (int)wv[11] };
        i32x4 hi1 = { (int)wv[12], (int)wv[13], (int)wv[14], (int)wv[15] };
        *(i32x4*)(d0) = lo0; *(i32x4*)(d0 + 16) = lo1;
        *(i32x4*)(d1) = hi0; *(i32x4*)(d1 + 16) = hi1;
    }
}

// ---- fp8 GEMM: 128x128 tile, BK=64, 4 waves, MX 32x32x64, 3 blocks/CU ----
// acc = 2x2 f32x16 = 64 regs/wave -> ~140 total -> __launch_bounds__(256,3)
// gives 12 waves/CU (3 decorrelated blocks; R7->R8 showed decorrelation is the lever).
#define BM 128
#define BN 128
#define BK 64
#define A_TILE 8192                   // 128 rows x 64 B
#define BUF_BYTES A_TILE
#define SMEM_BYTES (2 * A_TILE)       // 16 KiB dbuf; 3 blocks = 48 KiB/CU

__device__ __forceinline__ void gload16(const uint8_t* src, uint8_t* ldst) {
    __builtin_amdgcn_global_load_lds(
        (const __attribute__((address_space(1))) uint32_t*)(uintptr_t)src,
        (__attribute__((address_space(3))) uint32_t*)(uintptr_t)ldst, 16, 0, 0);
}

#define WAITVM(N) asm volatile("s_waitcnt vmcnt(" #N ")" ::: "memory")
#define BARRIER() do { asm volatile("" ::: "memory"); __builtin_amdgcn_s_barrier(); \
                       asm volatile("" ::: "memory"); } while (0)

#define LDFRAG(dst, base, off) do {                                    \
    i32x4 _lo = *(const i32x4*)((base) + (off));                       \
    i32x4 _hi = *(const i32x4*)((base) + ((off) ^ 16));                \
    dst[0] = _lo[0]; dst[1] = _lo[1]; dst[2] = _lo[2]; dst[3] = _lo[3];\
    dst[4] = _hi[0]; dst[5] = _hi[1]; dst[6] = _hi[2]; dst[7] = _hi[3];\
} while (0)

#define LOADB(bv, src, koff) do {                                      \
    const uint8_t* _p = (src) + (koff);                                \
    i32x4 _l0 = *(const i32x4*)(_p);                                   \
    i32x4 _l1 = *(const i32x4*)(_p + 16);                               \
    bv[0] = _l0[0]; bv[1] = _l0[1]; bv[2] = _l0[2]; bv[3] = _l0[3];    \
    bv[4] = _l1[0]; bv[5] = _l1[1]; bv[6] = _l1[2]; bv[7] = _l1[3];    \
} while (0)

#define MFMA_MX(A, B, C) __builtin_amdgcn_mfma_scale_f32_32x32x64_f8f6f4( \
    (A), (B), (C), 0, 0, 0, (int)0x7f7f7f7f, 0, (int)0x7f7f7f7f)

__global__ __launch_bounds__(256, 3) void fp8lin_gemm(
    const uint8_t* __restrict__ Aq,    // [M,K] fp8
    const uint8_t* __restrict__ Bpack, // packed W fragments
    const unsigned* __restrict__ amax_bits,
    const float* __restrict__ wscale,
    const float* __restrict__ bias,
    float* __restrict__ out,
    int M, int N, int K) {
    extern __shared__ __align__(16) uint8_t smem[];

    const int tid = threadIdx.x;
    const int wid = tid >> 6;
    const int lane = tid & 63;
    const int wm = wid >> 1;   // 0..1  (M-wave, 64 rows each)
    const int wn = wid & 1;    // 0..1  (N-wave, 64 cols each)

    // ---- bijective XCD swizzle (8192 blocks, %8==0) ----
    const int nbx = gridDim.x;                       // 128
    const int orig = blockIdx.y * nbx + blockIdx.x;
    const int cpx = (gridDim.x * gridDim.y) >> 3;    // 1024
    const int swzb = (orig & 7) * cpx + (orig >> 3);
    const int brow = (swzb / nbx) * BM;
    const int bcol = (swzb % nbx) * BN;

    // ---- A staging: granule p of row r holds global granule p ^ ((r>>1)&3) ----
    const int c0 = tid, c1 = tid + 256;
    const int r0 = c0 >> 2, r1 = c1 >> 2;
    const int sc0 = ((c0 & 3) ^ ((r0 >> 1) & 3)) * 16;
    const int sc1 = ((c1 & 3) ^ ((r1 >> 1) & 3)) * 16;
    const uint8_t* srcA0 = Aq + (size_t)(brow + r0) * K + sc0;
    const uint8_t* srcA1 = Aq + (size_t)(brow + r1) * K + sc1;
    const int ldsW = wid * 1024;

    // ---- LDS read addressing for A fragments ----
    const int l31 = lane & 31;
    const int q = lane >> 5;
    const int swzr = (l31 >> 1) & 3;
    const int posl = (2 * q) ^ swzr;
    const int offA = (wm * 64 + l31) * 64 + posl * 16;   // + mi*2048 (32 rows)

    // ---- B from pack: n-tile = bcol/32 + wn*2 + ni; 2048 B per 64-K granule ----
    const int NKT = K >> 6;
    const uint8_t* srcB0 = Bpack + ((size_t)((bcol >> 5) + wn * 2) * NKT * 64 + lane) * 32;
    const uint8_t* srcB1 = srcB0 + (size_t)NKT * 2048;

    f32x16 acc[2][2];
#pragma unroll
    for (int mi = 0; mi < 2; ++mi)
#pragma unroll
        for (int ni = 0; ni < 2; ++ni)
#pragma unroll
            for (int r = 0; r < 16; ++r) acc[mi][ni][r] = 0.0f;

    auto STAGEA = [&](int t, int ib) {   // 2 gload16 per thread
        size_t k0 = (size_t)t * BK;
        uint8_t* base = smem + ib * BUF_BYTES;
        gload16(srcA0 + k0, base + ldsW);
        gload16(srcA1 + k0, base + ldsW + 4096);
    };

    auto COMPUTE = [&](int ib, const i32x8& b0, const i32x8& b1) {
        const uint8_t* bA = smem + ib * BUF_BYTES;
        i32x8 aX, aY;
        LDFRAG(aX, bA, offA);
        LDFRAG(aY, bA, offA + 2048);
        __builtin_amdgcn_s_setprio(1);
        acc[0][0] = MFMA_MX(aX, b0, acc[0][0]);
        acc[1][0] = MFMA_MX(aY, b0, acc[1][0]);
        acc[0][1] = MFMA_MX(aX, b1, acc[0][1]);
        acc[1][1] = MFMA_MX(aY, b1, acc[1][1]);
        __builtin_amdgcn_s_setprio(0);
    };

    // Per tile: 6 VMEM ops/thread (2 gload16 + 4 B dwordx4) -> WAITVM(6) drains
    // exactly the previous tile's batch.
    const int NT = K / BK;  // 64 (even)
    i32x8 bE0, bE1, bO0, bO1;          // static names (rule #20)
    LOADB(bE0, srcB0, 0); LOADB(bE1, srcB1, 0);
    STAGEA(0, 0);
    for (int tp = 0; tp < NT; tp += 2) {
        // even tile tp: compute buf0/E, prefetch tile tp+1 -> buf1/O
        LOADB(bO0, srcB0, (size_t)(tp + 1) * 2048);
        LOADB(bO1, srcB1, (size_t)(tp + 1) * 2048);
        STAGEA(tp + 1, 1);
        WAITVM(6);
        BARRIER();
        COMPUTE(0, bE0, bE1);
        BARRIER();
        // odd tile tp+1: compute buf1/O, prefetch tile tp+2 -> buf0/E
        if (tp + 2 < NT) {
            LOADB(bE0, srcB0, (size_t)(tp + 2) * 2048);
            LOADB(bE1, srcB1, (size_t)(tp + 2) * 2048);
            STAGEA(tp + 2, 0);
            WAITVM(6);
        } else {
            WAITVM(0);
        }
        BARRIER();
        COMPUTE(1, bO0, bO1);
        BARRIER();
    }

    // ---- epilogue: 32x32 C/D layout col=lane&31, row=(reg&3)+8*(reg>>2)+4*q ----
    float s = (fmaxf(__uint_as_float(*amax_bits), 1e-12f) / FP8_MAX_V) * wscale[0];
    const int colg = bcol + wn * 64 + l31;
    const int rowg0 = brow + wm * 64 + 4 * q;
#pragma unroll
    for (int ni = 0; ni < 2; ++ni) {
        int col = colg + ni * 32;
        float bv = bias[col];
#pragma unroll
        for (int mi = 0; mi < 2; ++mi) {
            int rb = rowg0 + mi * 32;
#pragma unroll
            for (int reg = 0; reg < 16; ++reg) {
                int row = rb + (reg & 3) + 8 * (reg >> 2);
                __builtin_nontemporal_store(acc[mi][ni][reg] * s + bv,
                                            out + (size_t)row * N + col);
            }
        }
    }
}

extern "C" void kernel_launch(void* const* d_in, const int* in_sizes, int n_in,
                              void* d_out, int out_size, void* d_ws, size_t ws_size,
                              hipStream_t stream) {
    const float* x = (const float*)d_in[0];
    const void* w = d_in[1];
    const float* wscale = (const float*)d_in[2];
    const float* bias = (const float*)d_in[3];
    float* out = (float*)d_out;

    const int Bb = 4, S = 2048, K = 4096, N = 16384;
    const int M = Bb * S;
    const long nx = (long)M * K;

    unsigned* amax_bits = (unsigned*)d_ws;
    unsigned* wflag = (unsigned*)((char*)d_ws + 32);
    uchar4* xq = (uchar4*)((char*)d_ws + 256);
    uint8_t* pack = (uint8_t*)((char*)d_ws + 256 + nx);

    fp8lin_probe<<<1, 256, 0, stream>>>((const uint32_t*)w, wflag, amax_bits);
    fp8lin_amax<<<2048, 256, 0, stream>>>((const float4*)x, amax_bits, nx / 4);
    fp8lin_quant<<<2048, 256, 0, stream>>>((const float4*)x, amax_bits, xq, nx / 4);
    fp8lin_packw<<<2048, 256, 0, stream>>>(w, wflag, pack, N, K);

    dim3 grid(N / BN, M / BM);   // (128, 64) = 8192 blocks
    fp8lin_gemm<<<grid, 256, SMEM_BYTES, stream>>>((const uint8_t*)xq, pack,
                                                   amax_bits, wscale, bias, out, M, N, K);
}

// Round 14
// 820.552 us; speedup vs baseline: 3.4573x; 1.1521x over previous
//
#include <hip/hip_runtime.h>
#include <hip/hip_fp8.h>
#include <hip/hip_fp16.h>
#include <stdint.h>

#define FP8_MAX_V 448.0f

typedef float f32x16 __attribute__((ext_vector_type(16)));
typedef int i32x4 __attribute__((ext_vector_type(4)));
typedef int i32x8 __attribute__((ext_vector_type(8)));

__device__ __forceinline__ uint8_t cvt_fp8(float v) {
    return __hip_cvt_float_to_fp8(fminf(fmaxf(v, -FP8_MAX_V), FP8_MAX_V),
                                  __HIP_SATFINITE, __HIP_E4M3);
}

// ---------------- probe weight transport dtype + init amax ----------------
__global__ void fp8lin_probe(const uint32_t* __restrict__ w, unsigned* __restrict__ flag,
                             unsigned* __restrict__ amax_bits) {
    __shared__ unsigned s32, s16, s4;
    if (threadIdx.x == 0) { s32 = 0u; s16 = 0u; s4 = 0u; *amax_bits = 0u; }
    __syncthreads();
    unsigned o32 = 0u, o16 = 0u, o4 = 0u;
    for (int i = threadIdx.x; i < 4096; i += 256) {
        uint32_t v = w[i];
        o32 |= v & 0x000FFFFFu;
        uint32_t h0 = v & 0xFFFFu, h1 = v >> 16;
        o16 |= (h0 & 0x7Fu) | (h1 & 0x7Fu);
        o4  |= (h0 & 0x0Fu) | (h1 & 0x0Fu);
    }
    atomicOr(&s32, o32); atomicOr(&s16, o16); atomicOr(&s4, o4);
    __syncthreads();
    if (threadIdx.x == 0)
        *flag = (s32 == 0u) ? 0u : (s16 == 0u) ? 1u : (s4 == 0u) ? 2u : 3u;
}

// ---------------- amax (per-tensor, exact) ----------------
__global__ void fp8lin_amax(const float4* __restrict__ x, unsigned* __restrict__ amax_bits, long n4) {
    float m = 0.f;
    long stride = (long)gridDim.x * blockDim.x;
    for (long i = blockIdx.x * (long)blockDim.x + threadIdx.x; i < n4; i += stride) {
        float4 v = x[i];
        m = fmaxf(m, fmaxf(fmaxf(fabsf(v.x), fabsf(v.y)), fmaxf(fabsf(v.z), fabsf(v.w))));
    }
#pragma unroll
    for (int o = 32; o; o >>= 1) m = fmaxf(m, __shfl_xor(m, o));
    if ((threadIdx.x & 63) == 0) atomicMax(amax_bits, __float_as_uint(m));
}

// ---- quantize x -> fp8 AND write directly in MFMA-fragment pack order ----
// pack byte addr = (v*64 + q*32 + r)*32 + inner, v = mt*NKT + kt;
// unit u (4 bytes): b2 = u&7, r = (u>>3)&31, q = (u>>8)&1, v = u>>9.
// Writes fully coalesced in pack order; reads pull float4 from x (8 rows/wave).
__global__ void fp8lin_quantpack(const float* __restrict__ x, const unsigned* __restrict__ amax_bits,
                                 uchar4* __restrict__ apack, int M, int K) {
    float s = fmaxf(__uint_as_float(*amax_bits), 1e-12f) / FP8_MAX_V;
    const int NKT = K >> 6;
    const long units = ((long)M * K) >> 2;
    long stride = (long)gridDim.x * blockDim.x;
    for (long u = blockIdx.x * (long)blockDim.x + threadIdx.x; u < units; u += stride) {
        long b2 = u & 7;
        long r = (u >> 3) & 31;
        long q = (u >> 8) & 1;
        long v = u >> 9;
        long row = (v / NKT) * 32 + r;
        long k = (v % NKT) * 64 + q * 32 + b2 * 4;
        float4 t = *(const float4*)(x + row * (long)K + k);
        uchar4 o;
        o.x = cvt_fp8(t.x / s); o.y = cvt_fp8(t.y / s);
        o.z = cvt_fp8(t.z / s); o.w = cvt_fp8(t.w / s);
        apack[u] = o;
    }
}

// ---- convert + PACK weight into MFMA-fragment order (same layout as apack) ----
__global__ void fp8lin_packw(const void* __restrict__ wsrc, const unsigned* __restrict__ flag,
                             uint8_t* __restrict__ pack, int N, int K) {
    const int NKT = K >> 6;
    const long units = ((long)N * K) >> 6;
    unsigned f = *flag;
    long stride = (long)gridDim.x * blockDim.x;
    for (long u = blockIdx.x * (long)blockDim.x + threadIdx.x; u < units; u += stride) {
        int r = (int)(u & 31);
        long v = u >> 5;
        long row = (v / NKT) * 32 + r;
        long kbase = (long)(v % NKT) * 64;
        uint32_t wv[16];
        if (f == 0u) {
            const float4* s = (const float4*)((const float*)wsrc + row * K + kbase);
#pragma unroll
            for (int i = 0; i < 16; ++i) {
                float4 t = s[i];
                wv[i] = (uint32_t)cvt_fp8(t.x) | ((uint32_t)cvt_fp8(t.y) << 8) |
                        ((uint32_t)cvt_fp8(t.z) << 16) | ((uint32_t)cvt_fp8(t.w) << 24);
            }
        } else if (f == 1u) {
            const __half* s = (const __half*)wsrc + row * K + kbase;
#pragma unroll
            for (int i = 0; i < 16; ++i) {
                uint32_t a = 0;
#pragma unroll
                for (int j = 0; j < 4; ++j) a |= (uint32_t)cvt_fp8(__half2float(s[4 * i + j])) << (8 * j);
                wv[i] = a;
            }
        } else if (f == 2u) {
            const uint16_t* s = (const uint16_t*)wsrc + row * K + kbase;
#pragma unroll
            for (int i = 0; i < 16; ++i) {
                uint32_t a = 0;
#pragma unroll
                for (int j = 0; j < 4; ++j)
                    a |= (uint32_t)cvt_fp8(__uint_as_float((uint32_t)s[4 * i + j] << 16)) << (8 * j);
                wv[i] = a;
            }
        } else {
            const uint32_t* s = (const uint32_t*)((const uint8_t*)wsrc + row * K + kbase);
#pragma unroll
            for (int i = 0; i < 16; ++i) wv[i] = s[i];
        }
        uint8_t* d0 = pack + (v * 64 + r) * 32;
        uint8_t* d1 = pack + (v * 64 + 32 + r) * 32;
        i32x4 lo0 = { (int)wv[0], (int)wv[1], (int)wv[2], (int)wv[3] };
        i32x4 lo1 = { (int)wv[4], (int)wv[5], (int)wv[6], (int)wv[7] };
        i32x4 hi0 = { (int)wv[8], (int)wv[9], (int)wv[10], (int)wv[11] };
        i32x4 hi1 = { (int)wv[12], (int)wv[13], (int)wv[14], (int)wv[15] };
        *(i32x4*)(d0) = lo0; *(i32x4*)(d0 + 16) = lo1;
        *(i32x4*)(d1) = hi0; *(i32x4*)(d1 + 16) = hi1;
    }
}

// ---- fp8 GEMM: 256x128, 4 waves, MX 32x32x64 — ZERO barriers, ZERO LDS ----
// Both operands pre-packed in fragment order; each wave streams its fragments
// straight to registers (2 KB contiguous per wave-load). Depth-1 prefetch into
// the same static registers: loads issue after the MFMAs that consume them
// (WAR), landing during the next tile's wait. No __syncthreads in the K-loop,
// so the 8 resident waves/CU drift freely (R8's decorrelation, maximized).
#define BM 256
#define BN 128
#define BK 64

#define LOADF(bv, src, koff) do {                                      \
    const uint8_t* _p = (src) + (koff);                                \
    i32x4 _l0 = *(const i32x4*)(_p);                                   \
    i32x4 _l1 = *(const i32x4*)(_p + 16);                              \
    bv[0] = _l0[0]; bv[1] = _l0[1]; bv[2] = _l0[2]; bv[3] = _l0[3];    \
    bv[4] = _l1[0]; bv[5] = _l1[1]; bv[6] = _l1[2]; bv[7] = _l1[3];    \
} while (0)

#define MFMA_MX(A, B, C) __builtin_amdgcn_mfma_scale_f32_32x32x64_f8f6f4( \
    (A), (B), (C), 0, 0, 0, (int)0x7f7f7f7f, 0, (int)0x7f7f7f7f)

// Reg audit: acc 128 + A frags 32 + B frags 16 + addr ~25 = ~201 < 256 (2 waves/SIMD).
__global__ __launch_bounds__(256, 2) void fp8lin_gemm(
    const uint8_t* __restrict__ Apack,
    const uint8_t* __restrict__ Bpack,
    const unsigned* __restrict__ amax_bits,
    const float* __restrict__ wscale,
    const float* __restrict__ bias,
    float* __restrict__ out,
    int M, int N, int K) {
    const int tid = threadIdx.x;
    const int wid = tid >> 6;
    const int lane = tid & 63;
    const int wm = wid >> 1;   // 0..1  (M-wave, 128 rows)
    const int wn = wid & 1;    // 0..1  (N-wave, 64 cols)

    // ---- bijective XCD swizzle: same-brow blocks land on one XCD (A L2-resident)
    const int nbx = gridDim.x;                       // 128
    const int orig = blockIdx.y * nbx + blockIdx.x;
    const int cpx = (gridDim.x * gridDim.y) >> 3;    // 512
    const int swzb = (orig & 7) * cpx + (orig >> 3);
    const int brow = (swzb / nbx) * BM;
    const int bcol = (swzb % nbx) * BN;

    const int NKT = K >> 6;
    const int mt0 = (brow >> 5) + wm * 4;
    const uint8_t* pA0 = Apack + ((size_t)(mt0 + 0) * NKT * 64 + lane) * 32;
    const uint8_t* pA1 = Apack + ((size_t)(mt0 + 1) * NKT * 64 + lane) * 32;
    const uint8_t* pA2 = Apack + ((size_t)(mt0 + 2) * NKT * 64 + lane) * 32;
    const uint8_t* pA3 = Apack + ((size_t)(mt0 + 3) * NKT * 64 + lane) * 32;
    const uint8_t* pB0 = Bpack + ((size_t)((bcol >> 5) + wn * 2) * NKT * 64 + lane) * 32;
    const uint8_t* pB1 = pB0 + (size_t)NKT * 2048;

    f32x16 acc[4][2];
#pragma unroll
    for (int mi = 0; mi < 4; ++mi)
#pragma unroll
        for (int ni = 0; ni < 2; ++ni)
#pragma unroll
            for (int r = 0; r < 16; ++r) acc[mi][ni][r] = 0.0f;

    i32x8 a0, a1, a2, a3, b0, b1;      // static names (rule #20)
    LOADF(a0, pA0, 0); LOADF(a1, pA1, 0);
    LOADF(a2, pA2, 0); LOADF(a3, pA3, 0);
    LOADF(b0, pB0, 0); LOADF(b1, pB1, 0);

    const int NT = K / BK;  // 64
#pragma unroll 1
    for (int t = 0; t < NT; ++t) {
        __builtin_amdgcn_s_setprio(1);
        acc[0][0] = MFMA_MX(a0, b0, acc[0][0]);
        acc[1][0] = MFMA_MX(a1, b0, acc[1][0]);
        acc[2][0] = MFMA_MX(a2, b0, acc[2][0]);
        acc[3][0] = MFMA_MX(a3, b0, acc[3][0]);
        acc[0][1] = MFMA_MX(a0, b1, acc[0][1]);
        acc[1][1] = MFMA_MX(a1, b1, acc[1][1]);
        acc[2][1] = MFMA_MX(a2, b1, acc[2][1]);
        acc[3][1] = MFMA_MX(a3, b1, acc[3][1]);
        __builtin_amdgcn_s_setprio(0);
        if (t + 1 < NT) {
            size_t off = (size_t)(t + 1) * 2048;
            LOADF(a0, pA0, off); LOADF(a1, pA1, off);
            LOADF(a2, pA2, off); LOADF(a3, pA3, off);
            LOADF(b0, pB0, off); LOADF(b1, pB1, off);
        }
    }

    // ---- epilogue: 32x32 C/D layout col=lane&31, row=(reg&3)+8*(reg>>2)+4*q ----
    float s = (fmaxf(__uint_as_float(*amax_bits), 1e-12f) / FP8_MAX_V) * wscale[0];
    const int l31 = lane & 31;
    const int q = lane >> 5;
    const int colg = bcol + wn * 64 + l31;
    const int rowg0 = brow + wm * 128 + 4 * q;
#pragma unroll
    for (int ni = 0; ni < 2; ++ni) {
        int col = colg + ni * 32;
        float bv = bias[col];
#pragma unroll
        for (int mi = 0; mi < 4; ++mi) {
            int rb = rowg0 + mi * 32;
#pragma unroll
            for (int reg = 0; reg < 16; ++reg) {
                int row = rb + (reg & 3) + 8 * (reg >> 2);
                __builtin_nontemporal_store(acc[mi][ni][reg] * s + bv,
                                            out + (size_t)row * N + col);
            }
        }
    }
}

extern "C" void kernel_launch(void* const* d_in, const int* in_sizes, int n_in,
                              void* d_out, int out_size, void* d_ws, size_t ws_size,
                              hipStream_t stream) {
    const float* x = (const float*)d_in[0];
    const void* w = d_in[1];
    const float* wscale = (const float*)d_in[2];
    const float* bias = (const float*)d_in[3];
    float* out = (float*)d_out;

    const int Bb = 4, S = 2048, K = 4096, N = 16384;
    const int M = Bb * S;
    const long nx = (long)M * K;

    unsigned* amax_bits = (unsigned*)d_ws;
    unsigned* wflag = (unsigned*)((char*)d_ws + 32);
    uint8_t* apack = (uint8_t*)((char*)d_ws + 256);
    uint8_t* bpack = (uint8_t*)((char*)d_ws + 256 + nx);

    fp8lin_probe<<<1, 256, 0, stream>>>((const uint32_t*)w, wflag, amax_bits);
    fp8lin_amax<<<2048, 256, 0, stream>>>((const float4*)x, amax_bits, nx / 4);
    fp8lin_quantpack<<<2048, 256, 0, stream>>>(x, amax_bits, (uchar4*)apack, M, K);
    fp8lin_packw<<<2048, 256, 0, stream>>>(w, wflag, bpack, N, K);

    dim3 grid(N / BN, M / BM);   // (128, 32) = 4096 blocks
    fp8lin_gemm<<<grid, 256, 0, stream>>>(apack, bpack, amax_bits, wscale, bias, out, M, N, K);
}

// Round 15
// 805.318 us; speedup vs baseline: 3.5227x; 1.0189x over previous
//
#include <hip/hip_runtime.h>
#include <hip/hip_fp8.h>
#include <hip/hip_fp16.h>
#include <stdint.h>

#define FP8_MAX_V 448.0f

typedef float f32x16 __attribute__((ext_vector_type(16)));
typedef int i32x4 __attribute__((ext_vector_type(4)));
typedef int i32x8 __attribute__((ext_vector_type(8)));

__device__ __forceinline__ uint8_t cvt_fp8(float v) {
    return __hip_cvt_float_to_fp8(fminf(fmaxf(v, -FP8_MAX_V), FP8_MAX_V),
                                  __HIP_SATFINITE, __HIP_E4M3);
}

// ---------------- probe weight transport dtype + init amax ----------------
__global__ void fp8lin_probe(const uint32_t* __restrict__ w, unsigned* __restrict__ flag,
                             unsigned* __restrict__ amax_bits) {
    __shared__ unsigned s32, s16, s4;
    if (threadIdx.x == 0) { s32 = 0u; s16 = 0u; s4 = 0u; *amax_bits = 0u; }
    __syncthreads();
    unsigned o32 = 0u, o16 = 0u, o4 = 0u;
    for (int i = threadIdx.x; i < 4096; i += 256) {
        uint32_t v = w[i];
        o32 |= v & 0x000FFFFFu;
        uint32_t h0 = v & 0xFFFFu, h1 = v >> 16;
        o16 |= (h0 & 0x7Fu) | (h1 & 0x7Fu);
        o4  |= (h0 & 0x0Fu) | (h1 & 0x0Fu);
    }
    atomicOr(&s32, o32); atomicOr(&s16, o16); atomicOr(&s4, o4);
    __syncthreads();
    if (threadIdx.x == 0)
        *flag = (s32 == 0u) ? 0u : (s16 == 0u) ? 1u : (s4 == 0u) ? 2u : 3u;
}

// ---------------- amax (per-tensor, exact) ----------------
__global__ void fp8lin_amax(const float4* __restrict__ x, unsigned* __restrict__ amax_bits, long n4) {
    float m = 0.f;
    long stride = (long)gridDim.x * blockDim.x;
    for (long i = blockIdx.x * (long)blockDim.x + threadIdx.x; i < n4; i += stride) {
        float4 v = x[i];
        m = fmaxf(m, fmaxf(fmaxf(fabsf(v.x), fabsf(v.y)), fmaxf(fabsf(v.z), fabsf(v.w))));
    }
#pragma unroll
    for (int o = 32; o; o >>= 1) m = fmaxf(m, __shfl_xor(m, o));
    if ((threadIdx.x & 63) == 0) atomicMax(amax_bits, __float_as_uint(m));
}

// ---- quantize x -> fp8 AND write directly in MFMA-fragment pack order ----
__global__ void fp8lin_quantpack(const float* __restrict__ x, const unsigned* __restrict__ amax_bits,
                                 uchar4* __restrict__ apack, int M, int K) {
    float s = fmaxf(__uint_as_float(*amax_bits), 1e-12f) / FP8_MAX_V;
    const int NKT = K >> 6;
    const long units = ((long)M * K) >> 2;
    long stride = (long)gridDim.x * blockDim.x;
    for (long u = blockIdx.x * (long)blockDim.x + threadIdx.x; u < units; u += stride) {
        long b2 = u & 7;
        long r = (u >> 3) & 31;
        long q = (u >> 8) & 1;
        long v = u >> 9;
        long row = (v / NKT) * 32 + r;
        long k = (v % NKT) * 64 + q * 32 + b2 * 4;
        float4 t = *(const float4*)(x + row * (long)K + k);
        uchar4 o;
        o.x = cvt_fp8(t.x / s); o.y = cvt_fp8(t.y / s);
        o.z = cvt_fp8(t.z / s); o.w = cvt_fp8(t.w / s);
        apack[u] = o;
    }
}

// ---- convert + PACK weight into MFMA-fragment order (same layout as apack) ----
__global__ void fp8lin_packw(const void* __restrict__ wsrc, const unsigned* __restrict__ flag,
                             uint8_t* __restrict__ pack, int N, int K) {
    const int NKT = K >> 6;
    const long units = ((long)N * K) >> 6;
    unsigned f = *flag;
    long stride = (long)gridDim.x * blockDim.x;
    for (long u = blockIdx.x * (long)blockDim.x + threadIdx.x; u < units; u += stride) {
        int r = (int)(u & 31);
        long v = u >> 5;
        long row = (v / NKT) * 32 + r;
        long kbase = (long)(v % NKT) * 64;
        uint32_t wv[16];
        if (f == 0u) {
            const float4* s = (const float4*)((const float*)wsrc + row * K + kbase);
#pragma unroll
            for (int i = 0; i < 16; ++i) {
                float4 t = s[i];
                wv[i] = (uint32_t)cvt_fp8(t.x) | ((uint32_t)cvt_fp8(t.y) << 8) |
                        ((uint32_t)cvt_fp8(t.z) << 16) | ((uint32_t)cvt_fp8(t.w) << 24);
            }
        } else if (f == 1u) {
            const __half* s = (const __half*)wsrc + row * K + kbase;
#pragma unroll
            for (int i = 0; i < 16; ++i) {
                uint32_t a = 0;
#pragma unroll
                for (int j = 0; j < 4; ++j) a |= (uint32_t)cvt_fp8(__half2float(s[4 * i + j])) << (8 * j);
                wv[i] = a;
            }
        } else if (f == 2u) {
            const uint16_t* s = (const uint16_t*)wsrc + row * K + kbase;
#pragma unroll
            for (int i = 0; i < 16; ++i) {
                uint32_t a = 0;
#pragma unroll
                for (int j = 0; j < 4; ++j)
                    a |= (uint32_t)cvt_fp8(__uint_as_float((uint32_t)s[4 * i + j] << 16)) << (8 * j);
                wv[i] = a;
            }
        } else {
            const uint32_t* s = (const uint32_t*)((const uint8_t*)wsrc + row * K + kbase);
#pragma unroll
            for (int i = 0; i < 16; ++i) wv[i] = s[i];
        }
        uint8_t* d0 = pack + (v * 64 + r) * 32;
        uint8_t* d1 = pack + (v * 64 + 32 + r) * 32;
        i32x4 lo0 = { (int)wv[0], (int)wv[1], (int)wv[2], (int)wv[3] };
        i32x4 lo1 = { (int)wv[4], (int)wv[5], (int)wv[6], (int)wv[7] };
        i32x4 hi0 = { (int)wv[8], (int)wv[9], (int)wv[10], (int)wv[11] };
        i32x4 hi1 = { (int)wv[12], (int)wv[13], (int)wv[14], (int)wv[15] };
        *(i32x4*)(d0) = lo0; *(i32x4*)(d0 + 16) = lo1;
        *(i32x4*)(d1) = hi0; *(i32x4*)(d1 + 16) = hi1;
    }
}

// ---- fp8 GEMM: 256x128, 4 waves, MX 32x32x64 — no barriers/LDS, pipelined regs ----
// R14 diagnosis: depth-1 prefetch into the same regs = zero latency cover; every
// tile pays full load latency (wall 2870 cy vs 1100 cy MFMA). Here:
//   B frags: E/O double-buffer, loaded 2 tiles ahead (~1100 cy cover).
//   A frags: split halves, each reloaded right after its consumers issue
//            (~275+ cy cover each), FIFO-counted vmcnt(8)/vmcnt(8) per tile.
// Exactly 12 loads/tile in 3 groups of 4; queue walk verified (see waits).
#define BM 256
#define BN 128
#define BK 64

// uniform-base load: base wave-uniform, voff = lane*32 (saddr form saves VGPRs)
#define LDU(bv, ub, t) do {                                            \
    const uint8_t* _p = (ub) + (size_t)(t) * 2048 + voff;              \
    i32x4 _l0 = *(const i32x4*)(_p);                                   \
    i32x4 _l1 = *(const i32x4*)(_p + 16);                              \
    bv[0] = _l0[0]; bv[1] = _l0[1]; bv[2] = _l0[2]; bv[3] = _l0[3];    \
    bv[4] = _l1[0]; bv[5] = _l1[1]; bv[6] = _l1[2]; bv[7] = _l1[3];    \
} while (0)

#define WAITVM(N) asm volatile("s_waitcnt vmcnt(" #N ")" ::: "memory")

#define MFMA_MX(A, B, C) __builtin_amdgcn_mfma_scale_f32_32x32x64_f8f6f4( \
    (A), (B), (C), 0, 0, 0, (int)0x7f7f7f7f, 0, (int)0x7f7f7f7f)

// P1: first half (a0,a1 x b0,b1) ; P2: second half (a2,a3 x b0,b1)
#define P1(B0, B1) do {                               \
    __builtin_amdgcn_s_setprio(1);                    \
    acc[0][0] = MFMA_MX(a0, B0, acc[0][0]);           \
    acc[1][0] = MFMA_MX(a1, B0, acc[1][0]);           \
    acc[0][1] = MFMA_MX(a0, B1, acc[0][1]);           \
    acc[1][1] = MFMA_MX(a1, B1, acc[1][1]);           \
    __builtin_amdgcn_s_setprio(0); } while (0)
#define P2(B0, B1) do {                               \
    __builtin_amdgcn_s_setprio(1);                    \
    acc[2][0] = MFMA_MX(a2, B0, acc[2][0]);           \
    acc[3][0] = MFMA_MX(a3, B0, acc[3][0]);           \
    acc[2][1] = MFMA_MX(a2, B1, acc[2][1]);           \
    acc[3][1] = MFMA_MX(a3, B1, acc[3][1]);           \
    __builtin_amdgcn_s_setprio(0); } while (0)

__global__ __launch_bounds__(256, 2) void fp8lin_gemm(
    const uint8_t* __restrict__ Apack,
    const uint8_t* __restrict__ Bpack,
    const unsigned* __restrict__ amax_bits,
    const float* __restrict__ wscale,
    const float* __restrict__ bias,
    float* __restrict__ out,
    int M, int N, int K) {
    const int tid = threadIdx.x;
    const int wid = tid >> 6;
    const int lane = tid & 63;
    const int wm = wid >> 1;   // 0..1
    const int wn = wid & 1;    // 0..1

    // ---- bijective XCD swizzle ----
    const int nbx = gridDim.x;                       // 128
    const int orig = blockIdx.y * nbx + blockIdx.x;
    const int cpx = (gridDim.x * gridDim.y) >> 3;    // 512
    const int swzb = (orig & 7) * cpx + (orig >> 3);
    const int brow = (swzb / nbx) * BM;
    const int bcol = (swzb % nbx) * BN;

    const int NKT = K >> 6;
    const size_t TSTRIDE = (size_t)NKT * 2048;
    const int mt0 = (brow >> 5) + wm * 4;
    const uint8_t* uA0 = Apack + (size_t)(mt0 + 0) * TSTRIDE;
    const uint8_t* uA1 = Apack + (size_t)(mt0 + 1) * TSTRIDE;
    const uint8_t* uA2 = Apack + (size_t)(mt0 + 2) * TSTRIDE;
    const uint8_t* uA3 = Apack + (size_t)(mt0 + 3) * TSTRIDE;
    const uint8_t* uB0 = Bpack + (size_t)((bcol >> 5) + wn * 2) * TSTRIDE;
    const uint8_t* uB1 = uB0 + TSTRIDE;
    const int voff = lane * 32;

    f32x16 acc[4][2];
#pragma unroll
    for (int mi = 0; mi < 4; ++mi)
#pragma unroll
        for (int ni = 0; ni < 2; ++ni)
#pragma unroll
            for (int r = 0; r < 16; ++r) acc[mi][ni][r] = 0.0f;

    i32x8 a0, a1, a2, a3, bE0, bE1, bO0, bO1;   // static names (rule #20)

    // ---- prologue: queue = [bE(0), a0a1(0), a2a3(0), bO(1)] = 16 outstanding
    LDU(bE0, uB0, 0); LDU(bE1, uB1, 0);
    LDU(a0, uA0, 0);  LDU(a1, uA1, 0);
    LDU(a2, uA2, 0);  LDU(a3, uA3, 0);
    LDU(bO0, uB0, 1); LDU(bO1, uB1, 1);

    const int NT = K / BK;  // 64 (even)
#pragma unroll 1
    for (int tp = 0; tp < NT; tp += 2) {
        // ===== even tile tp (B = E set) =====
        WAITVM(8);                       // retire bE(tp) + a0a1(tp)
        P1(bE0, bE1);
        LDU(a0, uA0, tp + 1); LDU(a1, uA1, tp + 1);       // 4 loads
        WAITVM(8);                       // retire a2a3(tp)
        P2(bE0, bE1);
        LDU(a2, uA2, tp + 1); LDU(a3, uA3, tp + 1);       // 4 loads
        if (tp + 2 < NT) {
            LDU(bE0, uB0, tp + 2); LDU(bE1, uB1, tp + 2); // 4 loads
            // ===== odd tile tp+1 (B = O set) =====
            WAITVM(8);                   // retire bO(tp+1) + a0a1(tp+1)
            P1(bO0, bO1);
            LDU(a0, uA0, tp + 2); LDU(a1, uA1, tp + 2);
            WAITVM(8);                   // retire a2a3(tp+1)
            P2(bO0, bO1);
            LDU(a2, uA2, tp + 2); LDU(a3, uA3, tp + 2);
            LDU(bO0, uB0, tp + 3); LDU(bO1, uB1, tp + 3); // tp+3 <= NT-1 here
        } else {
            // tail: pending = [bO(NT-1), a0a1(NT-1), a2a3(NT-1)] = 12
            WAITVM(4);                   // retire bO + a0a1
            P1(bO0, bO1);
            WAITVM(0);                   // retire a2a3
            P2(bO0, bO1);
        }
    }

    // ---- epilogue: 32x32 C/D layout col=lane&31, row=(reg&3)+8*(reg>>2)+4*q ----
    float s = (fmaxf(__uint_as_float(*amax_bits), 1e-12f) / FP8_MAX_V) * wscale[0];
    const int l31 = lane & 31;
    const int q = lane >> 5;
    const int colg = bcol + wn * 64 + l31;
    const int rowg0 = brow + wm * 128 + 4 * q;
#pragma unroll
    for (int ni = 0; ni < 2; ++ni) {
        int col = colg + ni * 32;
        float bv = bias[col];
#pragma unroll
        for (int mi = 0; mi < 4; ++mi) {
            int rb = rowg0 + mi * 32;
#pragma unroll
            for (int reg = 0; reg < 16; ++reg) {
                int row = rb + (reg & 3) + 8 * (reg >> 2);
                __builtin_nontemporal_store(acc[mi][ni][reg] * s + bv,
                                            out + (size_t)row * N + col);
            }
        }
    }
}

extern "C" void kernel_launch(void* const* d_in, const int* in_sizes, int n_in,
                              void* d_out, int out_size, void* d_ws, size_t ws_size,
                              hipStream_t stream) {
    const float* x = (const float*)d_in[0];
    const void* w = d_in[1];
    const float* wscale = (const float*)d_in[2];
    const float* bias = (const float*)d_in[3];
    float* out = (float*)d_out;

    const int Bb = 4, S = 2048, K = 4096, N = 16384;
    const int M = Bb * S;
    const long nx = (long)M * K;

    unsigned* amax_bits = (unsigned*)d_ws;
    unsigned* wflag = (unsigned*)((char*)d_ws + 32);
    uint8_t* apack = (uint8_t*)((char*)d_ws + 256);
    uint8_t* bpack = (uint8_t*)((char*)d_ws + 256 + nx);

    fp8lin_probe<<<1, 256, 0, stream>>>((const uint32_t*)w, wflag, amax_bits);
    fp8lin_amax<<<2048, 256, 0, stream>>>((const float4*)x, amax_bits, nx / 4);
    fp8lin_quantpack<<<2048, 256, 0, stream>>>(x, amax_bits, (uchar4*)apack, M, K);
    fp8lin_packw<<<2048, 256, 0, stream>>>(w, wflag, bpack, N, K);

    dim3 grid(N / BN, M / BM);   // (128, 32) = 4096 blocks
    fp8lin_gemm<<<grid, 256, 0, stream>>>(apack, bpack, amax_bits, wscale, bias, out, M, N, K);
}